// Round 3
// baseline (283.527 us; speedup 1.0000x reference)
//
#include <hip/hip_runtime.h>

#define DIM 64
#define BSHIFT 8                 // bucket = dst >> 8  (node range 256/bucket)
#define MAXNB 1024               // max coarse buckets (N <= 262144)
#define CHUNK 4096               // edges per block in hist/scatter passes
#define EPT (CHUNK / 256)        // edges per thread in those passes (=16)
#define DBINS 64                 // degree bins for divergence sort

// ---------------------------------------------------------------------------
// bf16 helpers (OCP bf16 = top 16 bits of fp32, RNE)
// ---------------------------------------------------------------------------
__device__ inline unsigned packbf(float a, float b) {
    unsigned ua = __float_as_uint(a), ub = __float_as_uint(b);
    unsigned ra = (ua + 0x7FFFu + ((ua >> 16) & 1u)) >> 16;
    unsigned rb = (ub + 0x7FFFu + ((ub >> 16) & 1u)) >> 16;
    return ra | (rb << 16);
}
__device__ inline void unpackbf(unsigned u, float& lo, float& hi) {
    lo = __uint_as_float(u << 16);
    hi = __uint_as_float(u & 0xFFFF0000u);
}
// s[0..7] += 8 bf16 (one uint4)
__device__ inline void acc_row(const uint4 v, float* s) {
    float lo, hi;
    unpackbf(v.x, lo, hi); s[0] += lo; s[1] += hi;
    unpackbf(v.y, lo, hi); s[2] += lo; s[3] += hi;
    unpackbf(v.z, lo, hi); s[4] += lo; s[5] += hi;
    unpackbf(v.w, lo, hi); s[6] += lo; s[7] += hi;
}
// s[0..7] += m * (8 bf16)   (m = 0/1 tail mask -> fma, no branch)
__device__ inline void acc_row_m(const uint4 v, float m, float* s) {
    float lo, hi;
    unpackbf(v.x, lo, hi); s[0] = fmaf(m, lo, s[0]); s[1] = fmaf(m, hi, s[1]);
    unpackbf(v.y, lo, hi); s[2] = fmaf(m, lo, s[2]); s[3] = fmaf(m, hi, s[3]);
    unpackbf(v.z, lo, hi); s[4] = fmaf(m, lo, s[4]); s[5] = fmaf(m, hi, s[5]);
    unpackbf(v.w, lo, hi); s[6] = fmaf(m, lo, s[6]); s[7] = fmaf(m, hi, s[7]);
}

// ---------------------------------------------------------------------------
// K1: per-block bucket histogram.  H[k*nblocks + b] = count of chunk-b edges
// with dst-bucket k.  (bucket-major so the global scan yields contiguous
// bucket ranges)
// ---------------------------------------------------------------------------
__global__ __launch_bounds__(256) void block_hist_kernel(
        const int* __restrict__ col, int* __restrict__ H, int E, int NB,
        int nblocks) {
    __shared__ int h[MAXNB];
    int tid = threadIdx.x;
    for (int k = tid; k < NB; k += 256) h[k] = 0;
    __syncthreads();
    int base = blockIdx.x * CHUNK;
    #pragma unroll
    for (int k = 0; k < EPT; k++) {
        int e = base + tid + k * 256;
        if (e < E) atomicAdd(&h[col[e] >> BSHIFT], 1);
    }
    __syncthreads();
    for (int k = tid; k < NB; k += 256) H[(size_t)k * nblocks + blockIdx.x] = h[k];
}

// ---------------------------------------------------------------------------
// K2/K3/K4: 3-kernel exclusive scan of H[0..M) -> S ; T = tile sums (<=256)
// tiles are 1024 elements (4/thread) so nt <= 256 at CHUNK=4096
// ---------------------------------------------------------------------------
__global__ void scan_tile_sum_kernel(const int* __restrict__ H,
                                     int* __restrict__ T, int M) {
    int tid = threadIdx.x;
    int base = blockIdx.x * 1024 + tid * 4;
    int s = 0;
    #pragma unroll
    for (int k = 0; k < 4; k++)
        if (base + k < M) s += H[base + k];
    __shared__ int lds[256];
    lds[tid] = s;
    __syncthreads();
    for (int off = 128; off > 0; off >>= 1) {
        if (tid < off) lds[tid] += lds[tid + off];
        __syncthreads();
    }
    if (tid == 0) T[blockIdx.x] = lds[0];
}

// single block; also zeroes the degree histogram (runs before fine_fill)
__global__ void scan_tile_offsets_kernel(int* __restrict__ T, int nt,
                                         int* __restrict__ dhist) {
    __shared__ int lds[256];
    int tid = threadIdx.x;
    if (tid < DBINS) dhist[tid] = 0;
    int v = (tid < nt) ? T[tid] : 0;
    lds[tid] = v;
    __syncthreads();
    for (int off = 1; off < 256; off <<= 1) {
        int t = (tid >= off) ? lds[tid - off] : 0;
        __syncthreads();
        lds[tid] += t;
        __syncthreads();
    }
    if (tid < nt) T[tid] = lds[tid] - v;  // exclusive
}

// also emits bbase[k] = S[k*nblocks] and bbase[NB] = E (folds old bbase launch)
__global__ void scan_final_kernel(const int* __restrict__ H,
                                  const int* __restrict__ T,
                                  int* __restrict__ S,
                                  int* __restrict__ bbase, int M, int nblocks,
                                  int NB, int E) {
    int tid = threadIdx.x;
    int base = blockIdx.x * 1024 + tid * 4;
    int c[4];
    int local = 0;
    #pragma unroll
    for (int k = 0; k < 4; k++) {
        c[k] = (base + k < M) ? H[base + k] : 0;
        local += c[k];
    }
    __shared__ int lds[256];
    lds[tid] = local;
    __syncthreads();
    for (int off = 1; off < 256; off <<= 1) {
        int t = (tid >= off) ? lds[tid - off] : 0;
        __syncthreads();
        lds[tid] += t;
        __syncthreads();
    }
    int excl = lds[tid] - local + T[blockIdx.x];
    #pragma unroll
    for (int k = 0; k < 4; k++) {
        int idx = base + k;
        if (idx < M) {
            S[idx] = excl;
            if (idx % nblocks == 0) bbase[idx / nblocks] = excl;
        }
        excl += c[k];
    }
    if (blockIdx.x == 0 && tid == 0) bbase[NB] = E;
}

// ---------------------------------------------------------------------------
// K5: deterministic binned scatter. Bases come from S — zero global atomics.
// pairs[pos] = src | (dst_local << 24)
// ---------------------------------------------------------------------------
__global__ __launch_bounds__(256) void scatter_binned_kernel(
        const int* __restrict__ row, const int* __restrict__ col,
        const int* __restrict__ S, unsigned* __restrict__ pairs, int E,
        int NB, int nblocks) {
    __shared__ unsigned stage[CHUNK];
    __shared__ int gdst[CHUNK];
    __shared__ int hist[MAXNB];   // counts -> local cursor
    __shared__ int pfx[MAXNB];    // exclusive local prefix
    __shared__ int gbase[MAXNB];  // per-(block,bucket) base (scan scratch too)
    int tid = threadIdx.x;
    int bid = blockIdx.x;
    int base = bid * CHUNK;
    int nloc = min(CHUNK, E - base);

    for (int b = tid; b < NB; b += 256) hist[b] = 0;
    __syncthreads();

    unsigned vals[EPT];
    int keys[EPT];
    #pragma unroll
    for (int k = 0; k < EPT; k++) {
        int e = base + tid + k * 256;
        if (e < E) {
            int d = col[e];
            int s = row[e];
            keys[k] = d >> BSHIFT;
            vals[k] = (unsigned)s | ((unsigned)(d & 255) << 24);
            atomicAdd(&hist[keys[k]], 1);
        } else {
            keys[k] = -1;
        }
    }
    __syncthreads();

    // exclusive scan of hist -> pfx (4 buckets/thread; scratch = gbase)
    int b0 = tid * 4;
    int c4[4];
    int loc = 0;
    #pragma unroll
    for (int k = 0; k < 4; k++) {
        c4[k] = (b0 + k < NB) ? hist[b0 + k] : 0;
        loc += c4[k];
    }
    gbase[tid] = loc;
    __syncthreads();
    for (int off = 1; off < 256; off <<= 1) {
        int t = (tid >= off) ? gbase[tid - off] : 0;
        __syncthreads();
        gbase[tid] += t;
        __syncthreads();
    }
    int excl = gbase[tid] - loc;
    #pragma unroll
    for (int k = 0; k < 4; k++) {
        if (b0 + k < NB) pfx[b0 + k] = excl;
        excl += c4[k];
    }
    __syncthreads();

    // deterministic global bases + init local cursors
    for (int b = tid; b < NB; b += 256) {
        gbase[b] = S[(size_t)b * nblocks + bid];
        hist[b] = pfx[b];
    }
    __syncthreads();

    // bin into LDS (bucket-sorted)
    #pragma unroll
    for (int k = 0; k < EPT; k++) {
        if (keys[k] >= 0) {
            int slot = atomicAdd(&hist[keys[k]], 1);
            stage[slot] = vals[k];
            gdst[slot] = gbase[keys[k]] + (slot - pfx[keys[k]]);
        }
    }
    __syncthreads();

    // sequential runs per bucket
    for (int s = tid; s < nloc; s += 256) pairs[gdst[s]] = stage[s];
}

// ---------------------------------------------------------------------------
// K6: fine fill — one workgroup per bucket; LDS count/scan/cursors;
// produces row_ptr (degree = diff), dst-grouped csr_src, degree histogram
// (for the divergence sort), AND writes z0 = deg^{-1/2} * emb (bf16)
// for its 256 nodes (folded prescale).
// ---------------------------------------------------------------------------
__global__ __launch_bounds__(256) void fine_fill_kernel(
        const unsigned* __restrict__ pairs, const int* __restrict__ bbase,
        int* __restrict__ row_ptr, int* __restrict__ csr_src,
        const float4* __restrict__ emb4, uint4* __restrict__ z4,
        int* __restrict__ dhist, int N, int E) {
    __shared__ int cnt[256];
    __shared__ int cur[256];
    __shared__ float wds[256];
    __shared__ int dh[DBINS];
    int b = blockIdx.x;
    int tid = threadIdx.x;
    int beg = bbase[b], end = bbase[b + 1];
    cnt[tid] = 0;
    if (tid < DBINS) dh[tid] = 0;
    __syncthreads();
    for (int j = beg + tid; j < end; j += 256)
        atomicAdd(&cnt[pairs[j] >> 24], 1);
    __syncthreads();
    int v = cnt[tid];
    wds[tid] = (v > 0) ? rsqrtf((float)v) : 0.0f;
    int node0 = (b << BSHIFT) + tid;
    if (node0 < N) atomicAdd(&dh[min(v, DBINS - 1)], 1);
    for (int off = 1; off < 256; off <<= 1) {
        int t = (tid >= off) ? cnt[tid - off] : 0;
        __syncthreads();
        cnt[tid] += t;
        __syncthreads();
    }
    int excl = cnt[tid] - v;
    if (node0 < N) row_ptr[node0] = beg + excl;
    cur[tid] = beg + excl;
    __syncthreads();
    if (tid < DBINS && dh[tid] > 0) atomicAdd(&dhist[tid], dh[tid]);
    for (int j = beg + tid; j < end; j += 256) {
        unsigned p = pairs[j];
        int pos = atomicAdd(&cur[p >> 24], 1);
        csr_src[pos] = (int)(p & 0xFFFFFFu);
    }
    if (b == 0 && tid == 0) row_ptr[N] = E;

    // folded prescale: 8-lane group per node, 32 nodes per pass
    int gl = tid & 7;
    #pragma unroll
    for (int g = 0; g < 8; g++) {
        int il = g * 32 + (tid >> 3);
        int node = (b << BSHIFT) + il;
        if (node < N) {
            float wd = wds[il];
            size_t eo = (size_t)node * 16 + gl * 2;
            float4 a = emb4[eo], c = emb4[eo + 1];
            uint4 z;
            z.x = packbf(a.x * wd, a.y * wd);
            z.y = packbf(a.z * wd, a.w * wd);
            z.z = packbf(c.x * wd, c.y * wd);
            z.w = packbf(c.z * wd, c.w * wd);
            z4[(size_t)node * 8 + gl] = z;
        }
    }
}

// ---------------------------------------------------------------------------
// K7: exclusive scan of the 64-bin degree histogram -> dcursor (bin bases)
// ---------------------------------------------------------------------------
__global__ void dscan_kernel(const int* __restrict__ dhist,
                             int* __restrict__ dcursor) {
    if (threadIdx.x == 0) {
        int acc = 0;
        for (int k = 0; k < DBINS; k++) {
            dcursor[k] = acc;
            acc += dhist[k];
        }
    }
}

// ---------------------------------------------------------------------------
// K8: build degree-sorted permutation.  perm[pos] = node, pos grouped by
// degree bin.  Within-bin order nondeterministic (harmless: each node's
// output is computed independently and written once).
// ---------------------------------------------------------------------------
__global__ __launch_bounds__(256) void perm_kernel(
        const int* __restrict__ row_ptr, int* __restrict__ dcursor,
        int* __restrict__ perm, int N) {
    __shared__ int lh[DBINS];     // block hist
    __shared__ int lbase[DBINS];  // block's global base per bin
    __shared__ int lcur[DBINS];   // block-local cursor per bin
    int tid = threadIdx.x;
    int node = blockIdx.x * 256 + tid;
    int bin = -1;
    if (node < N) {
        int deg = row_ptr[node + 1] - row_ptr[node];
        bin = min(deg, DBINS - 1);
    }
    if (tid < DBINS) { lh[tid] = 0; lcur[tid] = 0; }
    __syncthreads();
    if (bin >= 0) atomicAdd(&lh[bin], 1);
    __syncthreads();
    if (tid < DBINS && lh[tid] > 0) lbase[tid] = atomicAdd(&dcursor[tid], lh[tid]);
    __syncthreads();
    if (bin >= 0) {
        int r = atomicAdd(&lcur[bin], 1);
        perm[lbase[bin] + r] = node;
    }
}

// ---------------------------------------------------------------------------
// software-pipelined gather-sum over one CSR row (8-lane group) on bf16 rows:
// clamped-index quads (tail masked by fma), next quad's indices prefetched
// while current gathers are in flight.
// ---------------------------------------------------------------------------
__device__ inline void row_gather_sum(const int* __restrict__ csr_src,
                                      const uint4* __restrict__ z4, int b,
                                      int e, int gl, float* s) {
    if (b >= e) return;
    int e1 = e - 1;
    int j = b;
    int i0 = csr_src[j];
    int i1 = csr_src[min(j + 1, e1)];
    int i2 = csr_src[min(j + 2, e1)];
    int i3 = csr_src[min(j + 3, e1)];
    while (j < e) {
        uint4 v0 = z4[(size_t)i0 * 8 + gl];
        uint4 v1 = z4[(size_t)i1 * 8 + gl];
        uint4 v2 = z4[(size_t)i2 * 8 + gl];
        uint4 v3 = z4[(size_t)i3 * 8 + gl];
        int jn = j + 4;
        if (jn < e) {  // prefetch next quad (independent of gathers above)
            i0 = csr_src[jn];
            i1 = csr_src[min(jn + 1, e1)];
            i2 = csr_src[min(jn + 2, e1)];
            i3 = csr_src[min(jn + 3, e1)];
        }
        float m1 = (j + 1 < e) ? 1.0f : 0.0f;
        float m2 = (j + 2 < e) ? 1.0f : 0.0f;
        float m3 = (j + 3 < e) ? 1.0f : 0.0f;
        acc_row(v0, s);
        acc_row_m(v1, m1, s);
        acc_row_m(v2, m2, s);
        acc_row_m(v3, m3, s);
        j = jn;
    }
}

// ---------------------------------------------------------------------------
// pull SpMM on bf16 z (degree-sorted order):  z_next[i] = (sum z[src]) / deg
// ---------------------------------------------------------------------------
__global__ __launch_bounds__(256) void spmm_pull_kernel(
        const int* __restrict__ perm, const int* __restrict__ row_ptr,
        const int* __restrict__ csr_src, const uint4* __restrict__ z4,
        uint4* __restrict__ znext4, int N) {
    int t = blockIdx.x * blockDim.x + threadIdx.x;
    int g = t >> 3;
    int gl = t & 7;
    if (g >= N) return;
    int i = perm[g];
    int b = row_ptr[i], e = row_ptr[i + 1];
    float s[8] = {0, 0, 0, 0, 0, 0, 0, 0};
    row_gather_sum(csr_src, z4, b, e, gl, s);
    int deg = e - b;
    float wd = (deg > 0) ? rsqrtf((float)deg) : 0.0f;
    float w2 = wd * wd;
    uint4 z;
    z.x = packbf(s[0] * w2, s[1] * w2);
    z.y = packbf(s[2] * w2, s[3] * w2);
    z.z = packbf(s[4] * w2, s[5] * w2);
    z.w = packbf(s[6] * w2, s[7] * w2);
    znext4[(size_t)i * 8 + gl] = z;
}

// ---------------------------------------------------------------------------
// fused layer-3 SpMM + combine (degree-sorted order):
//   t = sum_{nbr} z2[src];  acc = emb + sqrt(deg)*(z1+z2) + wd*t   (bf16)
// ---------------------------------------------------------------------------
__global__ __launch_bounds__(256) void spmm_combine_kernel(
        const int* __restrict__ perm, const int* __restrict__ row_ptr,
        const int* __restrict__ csr_src, const uint4* __restrict__ z2,
        const uint4* __restrict__ z1, const float4* __restrict__ emb4,
        uint4* __restrict__ accb, int N) {
    int t = blockIdx.x * blockDim.x + threadIdx.x;
    int g = t >> 3;
    int gl = t & 7;
    if (g >= N) return;
    int i = perm[g];
    int b = row_ptr[i], e = row_ptr[i + 1];
    float s[8] = {0, 0, 0, 0, 0, 0, 0, 0};
    row_gather_sum(csr_src, z2, b, e, gl, s);
    int deg = e - b;
    float wd = (deg > 0) ? rsqrtf((float)deg) : 0.0f;
    float sq = (deg > 0) ? sqrtf((float)deg) : 0.0f;
    size_t zo = (size_t)i * 8 + gl;
    uint4 a1 = z1[zo], a2 = z2[zo];
    float w[8] = {0, 0, 0, 0, 0, 0, 0, 0};
    acc_row(a1, w); acc_row(a2, w);
    size_t eo = (size_t)i * 16 + gl * 2;
    float4 e0 = emb4[eo], e1 = emb4[eo + 1];
    float r0 = e0.x + sq * w[0] + wd * s[0];
    float r1 = e0.y + sq * w[1] + wd * s[1];
    float r2 = e0.z + sq * w[2] + wd * s[2];
    float r3 = e0.w + sq * w[3] + wd * s[3];
    float r4 = e1.x + sq * w[4] + wd * s[4];
    float r5 = e1.y + sq * w[5] + wd * s[5];
    float r6 = e1.z + sq * w[6] + wd * s[6];
    float r7 = e1.w + sq * w[7] + wd * s[7];
    uint4 z;
    z.x = packbf(r0, r1);
    z.y = packbf(r2, r3);
    z.z = packbf(r4, r5);
    z.w = packbf(r6, r7);
    accb[zo] = z;
}

// ---------------------------------------------------------------------------
// logits[p] = alpha^2 * dot(acc[u], acc[i]) ; 8-lane group per pair
// ---------------------------------------------------------------------------
__global__ __launch_bounds__(256) void score_kernel(
        const int* __restrict__ batch, const uint4* __restrict__ accb,
        float* __restrict__ out, int P) {
    int t = blockIdx.x * blockDim.x + threadIdx.x;
    int p = t >> 3;
    int gl = t & 7;
    if (p >= P) return;
    int u = batch[(size_t)p * 3 + 0];
    int it = batch[(size_t)p * 3 + 1];
    uint4 a = accb[(size_t)u * 8 + gl];
    uint4 b = accb[(size_t)it * 8 + gl];
    float sa[8] = {0, 0, 0, 0, 0, 0, 0, 0};
    float sb[8] = {0, 0, 0, 0, 0, 0, 0, 0};
    acc_row(a, sa);
    acc_row(b, sb);
    float s = sa[0] * sb[0] + sa[1] * sb[1] + sa[2] * sb[2] + sa[3] * sb[3] +
              sa[4] * sb[4] + sa[5] * sb[5] + sa[6] * sb[6] + sa[7] * sb[7];
    s += __shfl_xor(s, 4, 64);
    s += __shfl_xor(s, 2, 64);
    s += __shfl_xor(s, 1, 64);
    if (gl == 0) out[p] = s * 0.0625f;  // alpha^2, alpha = 1/(K_LAYERS+1)
}

extern "C" void kernel_launch(void* const* d_in, const int* in_sizes, int n_in,
                              void* d_out, int out_size, void* d_ws,
                              size_t ws_size, hipStream_t stream) {
    const float* emb = (const float*)d_in[0];
    const int* edge_index = (const int*)d_in[1];
    const int* batch = (const int*)d_in[2];
    float* out = (float*)d_out;

    const int N = in_sizes[0] / DIM;        // 200000
    const int E = in_sizes[1] / 2;          // 1250000
    const int P = out_size;                 // 4096 * 101
    const int NB = (N + 255) >> BSHIFT;     // 782 coarse buckets
    const int nblocks = (E + CHUNK - 1) / CHUNK;  // 306 edge chunks
    const int M = NB * nblocks;             // 239292 scan entries
    const int nt = (M + 1023) / 1024;       // 234 scan tiles (<=256)

    const int* row = edge_index;            // sources
    const int* col = edge_index + E;        // targets

    const size_t zbytes = (size_t)N * DIM * 2;  // bf16 row buffer (25.6 MB)

    auto align256 = [](size_t x) { return (x + 255) & ~(size_t)255; };
    char* ws = (char*)d_ws;
    uint4* z0   = (uint4*)ws; ws += align256(zbytes);
    uint4* z1   = (uint4*)ws; ws += align256(zbytes);
    uint4* z2   = (uint4*)ws; ws += align256(zbytes);
    uint4* accb = (uint4*)ws; ws += align256(zbytes);
    unsigned* pairs = (unsigned*)ws; ws += align256((size_t)E * 4);
    int* csr_src    = (int*)ws;      ws += align256((size_t)E * 4);
    int* row_ptr    = (int*)ws;      ws += align256((size_t)(N + 1) * 4);
    int* perm       = (int*)ws;      ws += align256((size_t)N * 4);
    int* H          = (int*)ws;      ws += align256((size_t)M * 4);
    int* S          = (int*)ws;      ws += align256((size_t)M * 4);
    int* T          = (int*)ws;      ws += align256(256 * 4);
    int* bbase      = (int*)ws;      ws += align256((size_t)(NB + 1) * 4);
    int* dhist      = (int*)ws;      ws += align256(DBINS * 4);
    int* dcursor    = (int*)ws;

    // --- deterministic radix CSR build (no memsets, no global atomics) ---
    block_hist_kernel<<<nblocks, 256, 0, stream>>>(col, H, E, NB, nblocks);
    scan_tile_sum_kernel<<<nt, 256, 0, stream>>>(H, T, M);
    scan_tile_offsets_kernel<<<1, 256, 0, stream>>>(T, nt, dhist);
    scan_final_kernel<<<nt, 256, 0, stream>>>(H, T, S, bbase, M, nblocks, NB, E);
    scatter_binned_kernel<<<nblocks, 256, 0, stream>>>(row, col, S, pairs, E,
                                                       NB, nblocks);
    // fine_fill also writes z0 = deg^{-1/2} * emb (folded prescale) + dhist
    fine_fill_kernel<<<NB, 256, 0, stream>>>(pairs, bbase, row_ptr, csr_src,
                                             (const float4*)emb, z0, dhist,
                                             N, E);

    // --- degree-sorted permutation (kills intra-wave divergence) ---
    dscan_kernel<<<1, 64, 0, stream>>>(dhist, dcursor);
    perm_kernel<<<(N + 255) / 256, 256, 0, stream>>>(row_ptr, dcursor, perm, N);

    const int nodeBlocks = (N * 8 + 255) / 256;  // 8-lane group per node

    // --- layers 1,2 pull-SpMM; layer 3 fused with combine ---
    spmm_pull_kernel<<<nodeBlocks, 256, 0, stream>>>(perm, row_ptr, csr_src,
                                                     z0, z1, N);
    spmm_pull_kernel<<<nodeBlocks, 256, 0, stream>>>(perm, row_ptr, csr_src,
                                                     z1, z2, N);
    spmm_combine_kernel<<<nodeBlocks, 256, 0, stream>>>(perm, row_ptr, csr_src,
                                                        z2, z1,
                                                        (const float4*)emb,
                                                        accb, N);

    // --- scoring ---
    score_kernel<<<(P * 8 + 255) / 256, 256, 0, stream>>>(batch, accb, out, P);
}

// Round 6
// 253.178 us; speedup vs baseline: 1.1199x; 1.1199x over previous
//
#include <hip/hip_runtime.h>

#define DIM 64
#define BSHIFT 8                 // bucket = dst >> 8  (node range 256/bucket)
#define MAXNB 1024               // max coarse buckets (N <= 262144)
#define CHUNK 4096               // edges per block in hist/scatter passes
#define EPT (CHUNK / 256)        // edges per thread in those passes (=16)

// ---------------------------------------------------------------------------
// bf16 helpers (OCP bf16 = top 16 bits of fp32, RNE)
// ---------------------------------------------------------------------------
__device__ inline unsigned packbf(float a, float b) {
    unsigned ua = __float_as_uint(a), ub = __float_as_uint(b);
    unsigned ra = (ua + 0x7FFFu + ((ua >> 16) & 1u)) >> 16;
    unsigned rb = (ub + 0x7FFFu + ((ub >> 16) & 1u)) >> 16;
    return ra | (rb << 16);
}
__device__ inline void unpackbf(unsigned u, float& lo, float& hi) {
    lo = __uint_as_float(u << 16);
    hi = __uint_as_float(u & 0xFFFF0000u);
}
// s[0..7] += 8 bf16 (one uint4)
__device__ inline void acc_row(const uint4 v, float* s) {
    float lo, hi;
    unpackbf(v.x, lo, hi); s[0] += lo; s[1] += hi;
    unpackbf(v.y, lo, hi); s[2] += lo; s[3] += hi;
    unpackbf(v.z, lo, hi); s[4] += lo; s[5] += hi;
    unpackbf(v.w, lo, hi); s[6] += lo; s[7] += hi;
}
// s[0..7] += m * (8 bf16)   (m = 0/1 tail mask -> fma, no branch)
__device__ inline void acc_row_m(const uint4 v, float m, float* s) {
    float lo, hi;
    unpackbf(v.x, lo, hi); s[0] = fmaf(m, lo, s[0]); s[1] = fmaf(m, hi, s[1]);
    unpackbf(v.y, lo, hi); s[2] = fmaf(m, lo, s[2]); s[3] = fmaf(m, hi, s[3]);
    unpackbf(v.z, lo, hi); s[4] = fmaf(m, lo, s[4]); s[5] = fmaf(m, hi, s[5]);
    unpackbf(v.w, lo, hi); s[6] = fmaf(m, lo, s[6]); s[7] = fmaf(m, hi, s[7]);
}

// ---------------------------------------------------------------------------
// K1: per-block bucket histogram.  H[k*nblocks + b] = count of chunk-b edges
// with dst-bucket k.  (bucket-major so the global scan yields contiguous
// bucket ranges)
// ---------------------------------------------------------------------------
__global__ __launch_bounds__(256) void block_hist_kernel(
        const int* __restrict__ col, int* __restrict__ H, int E, int NB,
        int nblocks) {
    __shared__ int h[MAXNB];
    int tid = threadIdx.x;
    for (int k = tid; k < NB; k += 256) h[k] = 0;
    __syncthreads();
    int base = blockIdx.x * CHUNK;
    #pragma unroll
    for (int k = 0; k < EPT; k++) {
        int e = base + tid + k * 256;
        if (e < E) atomicAdd(&h[col[e] >> BSHIFT], 1);
    }
    __syncthreads();
    for (int k = tid; k < NB; k += 256) H[(size_t)k * nblocks + blockIdx.x] = h[k];
}

// ---------------------------------------------------------------------------
// K2/K3/K4: 3-kernel exclusive scan of H[0..M) -> S ; T = tile sums (<=256)
// tiles are 1024 elements (4/thread) so nt <= 256 at CHUNK=4096
// ---------------------------------------------------------------------------
__global__ void scan_tile_sum_kernel(const int* __restrict__ H,
                                     int* __restrict__ T, int M) {
    int tid = threadIdx.x;
    int base = blockIdx.x * 1024 + tid * 4;
    int s = 0;
    #pragma unroll
    for (int k = 0; k < 4; k++)
        if (base + k < M) s += H[base + k];
    __shared__ int lds[256];
    lds[tid] = s;
    __syncthreads();
    for (int off = 128; off > 0; off >>= 1) {
        if (tid < off) lds[tid] += lds[tid + off];
        __syncthreads();
    }
    if (tid == 0) T[blockIdx.x] = lds[0];
}

__global__ void scan_tile_offsets_kernel(int* __restrict__ T, int nt) {
    __shared__ int lds[256];
    int tid = threadIdx.x;
    int v = (tid < nt) ? T[tid] : 0;
    lds[tid] = v;
    __syncthreads();
    for (int off = 1; off < 256; off <<= 1) {
        int t = (tid >= off) ? lds[tid - off] : 0;
        __syncthreads();
        lds[tid] += t;
        __syncthreads();
    }
    if (tid < nt) T[tid] = lds[tid] - v;  // exclusive
}

// also emits bbase[k] = S[k*nblocks] and bbase[NB] = E (folds old bbase launch)
__global__ void scan_final_kernel(const int* __restrict__ H,
                                  const int* __restrict__ T,
                                  int* __restrict__ S,
                                  int* __restrict__ bbase, int M, int nblocks,
                                  int NB, int E) {
    int tid = threadIdx.x;
    int base = blockIdx.x * 1024 + tid * 4;
    int c[4];
    int local = 0;
    #pragma unroll
    for (int k = 0; k < 4; k++) {
        c[k] = (base + k < M) ? H[base + k] : 0;
        local += c[k];
    }
    __shared__ int lds[256];
    lds[tid] = local;
    __syncthreads();
    for (int off = 1; off < 256; off <<= 1) {
        int t = (tid >= off) ? lds[tid - off] : 0;
        __syncthreads();
        lds[tid] += t;
        __syncthreads();
    }
    int excl = lds[tid] - local + T[blockIdx.x];
    #pragma unroll
    for (int k = 0; k < 4; k++) {
        int idx = base + k;
        if (idx < M) {
            S[idx] = excl;
            if (idx % nblocks == 0) bbase[idx / nblocks] = excl;
        }
        excl += c[k];
    }
    if (blockIdx.x == 0 && tid == 0) bbase[NB] = E;
}

// ---------------------------------------------------------------------------
// K5: deterministic binned scatter. Bases come from S — zero global atomics.
// pairs[pos] = src | (dst_local << 24)
// ---------------------------------------------------------------------------
__global__ __launch_bounds__(256) void scatter_binned_kernel(
        const int* __restrict__ row, const int* __restrict__ col,
        const int* __restrict__ S, unsigned* __restrict__ pairs, int E,
        int NB, int nblocks) {
    __shared__ unsigned stage[CHUNK];
    __shared__ int gdst[CHUNK];
    __shared__ int hist[MAXNB];   // counts -> local cursor
    __shared__ int pfx[MAXNB];    // exclusive local prefix
    __shared__ int gbase[MAXNB];  // per-(block,bucket) base (scan scratch too)
    int tid = threadIdx.x;
    int bid = blockIdx.x;
    int base = bid * CHUNK;
    int nloc = min(CHUNK, E - base);

    for (int b = tid; b < NB; b += 256) hist[b] = 0;
    __syncthreads();

    unsigned vals[EPT];
    int keys[EPT];
    #pragma unroll
    for (int k = 0; k < EPT; k++) {
        int e = base + tid + k * 256;
        if (e < E) {
            int d = col[e];
            int s = row[e];
            keys[k] = d >> BSHIFT;
            vals[k] = (unsigned)s | ((unsigned)(d & 255) << 24);
            atomicAdd(&hist[keys[k]], 1);
        } else {
            keys[k] = -1;
        }
    }
    __syncthreads();

    // exclusive scan of hist -> pfx (4 buckets/thread; scratch = gbase)
    int b0 = tid * 4;
    int c4[4];
    int loc = 0;
    #pragma unroll
    for (int k = 0; k < 4; k++) {
        c4[k] = (b0 + k < NB) ? hist[b0 + k] : 0;
        loc += c4[k];
    }
    gbase[tid] = loc;
    __syncthreads();
    for (int off = 1; off < 256; off <<= 1) {
        int t = (tid >= off) ? gbase[tid - off] : 0;
        __syncthreads();
        gbase[tid] += t;
        __syncthreads();
    }
    int excl = gbase[tid] - loc;
    #pragma unroll
    for (int k = 0; k < 4; k++) {
        if (b0 + k < NB) pfx[b0 + k] = excl;
        excl += c4[k];
    }
    __syncthreads();

    // deterministic global bases + init local cursors
    for (int b = tid; b < NB; b += 256) {
        gbase[b] = S[(size_t)b * nblocks + bid];
        hist[b] = pfx[b];
    }
    __syncthreads();

    // bin into LDS (bucket-sorted)
    #pragma unroll
    for (int k = 0; k < EPT; k++) {
        if (keys[k] >= 0) {
            int slot = atomicAdd(&hist[keys[k]], 1);
            stage[slot] = vals[k];
            gdst[slot] = gbase[keys[k]] + (slot - pfx[keys[k]]);
        }
    }
    __syncthreads();

    // sequential runs per bucket
    for (int s = tid; s < nloc; s += 256) pairs[gdst[s]] = stage[s];
}

// ---------------------------------------------------------------------------
// K6: fine fill — one workgroup per bucket; LDS count/scan/cursors;
// produces row_ptr (degree = diff) and dst-grouped csr_src, AND writes
// z0 = deg^{-1/2} * emb (bf16) for its 256 nodes (folded prescale —
// the streaming emb reads overlap the LDS-atomic/scatter latency).
// ---------------------------------------------------------------------------
__global__ __launch_bounds__(256) void fine_fill_kernel(
        const unsigned* __restrict__ pairs, const int* __restrict__ bbase,
        int* __restrict__ row_ptr, int* __restrict__ csr_src,
        const float4* __restrict__ emb4, uint4* __restrict__ z4, int N,
        int E) {
    __shared__ int cnt[256];
    __shared__ int cur[256];
    __shared__ float wds[256];
    int b = blockIdx.x;
    int tid = threadIdx.x;
    int beg = bbase[b], end = bbase[b + 1];
    cnt[tid] = 0;
    __syncthreads();
    for (int j = beg + tid; j < end; j += 256)
        atomicAdd(&cnt[pairs[j] >> 24], 1);
    __syncthreads();
    int v = cnt[tid];
    wds[tid] = (v > 0) ? rsqrtf((float)v) : 0.0f;
    for (int off = 1; off < 256; off <<= 1) {
        int t = (tid >= off) ? cnt[tid - off] : 0;
        __syncthreads();
        cnt[tid] += t;
        __syncthreads();
    }
    int excl = cnt[tid] - v;
    int node0 = (b << BSHIFT) + tid;
    if (node0 < N) row_ptr[node0] = beg + excl;
    cur[tid] = beg + excl;
    __syncthreads();
    for (int j = beg + tid; j < end; j += 256) {
        unsigned p = pairs[j];
        int pos = atomicAdd(&cur[p >> 24], 1);
        csr_src[pos] = (int)(p & 0xFFFFFFu);
    }
    if (b == 0 && tid == 0) row_ptr[N] = E;

    // folded prescale: 8-lane group per node, 32 nodes per pass
    int gl = tid & 7;
    #pragma unroll
    for (int g = 0; g < 8; g++) {
        int il = g * 32 + (tid >> 3);
        int node = (b << BSHIFT) + il;
        if (node < N) {
            float wd = wds[il];
            size_t eo = (size_t)node * 16 + gl * 2;
            float4 a = emb4[eo], c = emb4[eo + 1];
            uint4 z;
            z.x = packbf(a.x * wd, a.y * wd);
            z.y = packbf(a.z * wd, a.w * wd);
            z.z = packbf(c.x * wd, c.y * wd);
            z.w = packbf(c.z * wd, c.w * wd);
            z4[(size_t)node * 8 + gl] = z;
        }
    }
}

// ---------------------------------------------------------------------------
// 8-wide software-pipelined gather-sum over one CSR row (8-lane group) on
// bf16 rows: clamped-index octets (tail masked by fma), next octet's
// indices prefetched while current gathers are in flight.  8 outstanding
// 16B gathers per wave-group doubles MLP vs the old 4-wide loop; mean
// degree 6.25 means most rows finish in ONE iteration.
// ---------------------------------------------------------------------------
__device__ inline void row_gather_sum(const int* __restrict__ csr_src,
                                      const uint4* __restrict__ z4, int b,
                                      int e, int gl, float* s) {
    if (b >= e) return;
    int e1 = e - 1;
    int idx[8];
    #pragma unroll
    for (int k = 0; k < 8; k++) idx[k] = csr_src[min(b + k, e1)];
    int j = b;
    while (j < e) {
        uint4 v[8];
        #pragma unroll
        for (int k = 0; k < 8; k++) v[k] = z4[(size_t)idx[k] * 8 + gl];
        int jn = j + 8;
        if (jn < e) {  // prefetch next octet (independent of gathers above)
            #pragma unroll
            for (int k = 0; k < 8; k++) idx[k] = csr_src[min(jn + k, e1)];
        }
        acc_row(v[0], s);
        #pragma unroll
        for (int k = 1; k < 8; k++) {
            float m = (j + k < e) ? 1.0f : 0.0f;
            acc_row_m(v[k], m, s);
        }
        j = jn;
    }
}

// ---------------------------------------------------------------------------
// pull SpMM on bf16 z:  z_next[i] = (sum z[src]) / deg
// ---------------------------------------------------------------------------
__global__ __launch_bounds__(256) void spmm_pull_kernel(
        const int* __restrict__ row_ptr, const int* __restrict__ csr_src,
        const uint4* __restrict__ z4, uint4* __restrict__ znext4, int N) {
    int t = blockIdx.x * blockDim.x + threadIdx.x;
    int i = t >> 3;
    int gl = t & 7;
    if (i >= N) return;
    int b = row_ptr[i], e = row_ptr[i + 1];
    float s[8] = {0, 0, 0, 0, 0, 0, 0, 0};
    row_gather_sum(csr_src, z4, b, e, gl, s);
    int deg = e - b;
    float wd = (deg > 0) ? rsqrtf((float)deg) : 0.0f;
    float w2 = wd * wd;
    uint4 z;
    z.x = packbf(s[0] * w2, s[1] * w2);
    z.y = packbf(s[2] * w2, s[3] * w2);
    z.z = packbf(s[4] * w2, s[5] * w2);
    z.w = packbf(s[6] * w2, s[7] * w2);
    znext4[(size_t)i * 8 + gl] = z;
}

// ---------------------------------------------------------------------------
// fused layer-3 SpMM + combine:
//   t = sum_{nbr} z2[src];  acc = emb + sqrt(deg)*(z1+z2) + wd*t   (bf16)
// ---------------------------------------------------------------------------
__global__ __launch_bounds__(256) void spmm_combine_kernel(
        const int* __restrict__ row_ptr, const int* __restrict__ csr_src,
        const uint4* __restrict__ z2, const uint4* __restrict__ z1,
        const float4* __restrict__ emb4, uint4* __restrict__ accb, int N) {
    int t = blockIdx.x * blockDim.x + threadIdx.x;
    int i = t >> 3;
    int gl = t & 7;
    if (i >= N) return;
    int b = row_ptr[i], e = row_ptr[i + 1];
    float s[8] = {0, 0, 0, 0, 0, 0, 0, 0};
    row_gather_sum(csr_src, z2, b, e, gl, s);
    int deg = e - b;
    float wd = (deg > 0) ? rsqrtf((float)deg) : 0.0f;
    float sq = (deg > 0) ? sqrtf((float)deg) : 0.0f;
    size_t zo = (size_t)i * 8 + gl;
    uint4 a1 = z1[zo], a2 = z2[zo];
    float w[8] = {0, 0, 0, 0, 0, 0, 0, 0};
    acc_row(a1, w); acc_row(a2, w);
    size_t eo = (size_t)i * 16 + gl * 2;
    float4 e0 = emb4[eo], e1 = emb4[eo + 1];
    float r0 = e0.x + sq * w[0] + wd * s[0];
    float r1 = e0.y + sq * w[1] + wd * s[1];
    float r2 = e0.z + sq * w[2] + wd * s[2];
    float r3 = e0.w + sq * w[3] + wd * s[3];
    float r4 = e1.x + sq * w[4] + wd * s[4];
    float r5 = e1.y + sq * w[5] + wd * s[5];
    float r6 = e1.z + sq * w[6] + wd * s[6];
    float r7 = e1.w + sq * w[7] + wd * s[7];
    uint4 z;
    z.x = packbf(r0, r1);
    z.y = packbf(r2, r3);
    z.z = packbf(r4, r5);
    z.w = packbf(r6, r7);
    accb[zo] = z;
}

// ---------------------------------------------------------------------------
// logits[p] = alpha^2 * dot(acc[u], acc[i]) ; 8-lane group per pair
// ---------------------------------------------------------------------------
__global__ __launch_bounds__(256) void score_kernel(
        const int* __restrict__ batch, const uint4* __restrict__ accb,
        float* __restrict__ out, int P) {
    int t = blockIdx.x * blockDim.x + threadIdx.x;
    int p = t >> 3;
    int gl = t & 7;
    if (p >= P) return;
    int u = batch[(size_t)p * 3 + 0];
    int it = batch[(size_t)p * 3 + 1];
    uint4 a = accb[(size_t)u * 8 + gl];
    uint4 b = accb[(size_t)it * 8 + gl];
    float sa[8] = {0, 0, 0, 0, 0, 0, 0, 0};
    float sb[8] = {0, 0, 0, 0, 0, 0, 0, 0};
    acc_row(a, sa);
    acc_row(b, sb);
    float s = sa[0] * sb[0] + sa[1] * sb[1] + sa[2] * sb[2] + sa[3] * sb[3] +
              sa[4] * sb[4] + sa[5] * sb[5] + sa[6] * sb[6] + sa[7] * sb[7];
    s += __shfl_xor(s, 4, 64);
    s += __shfl_xor(s, 2, 64);
    s += __shfl_xor(s, 1, 64);
    if (gl == 0) out[p] = s * 0.0625f;  // alpha^2, alpha = 1/(K_LAYERS+1)
}

extern "C" void kernel_launch(void* const* d_in, const int* in_sizes, int n_in,
                              void* d_out, int out_size, void* d_ws,
                              size_t ws_size, hipStream_t stream) {
    const float* emb = (const float*)d_in[0];
    const int* edge_index = (const int*)d_in[1];
    const int* batch = (const int*)d_in[2];
    float* out = (float*)d_out;

    const int N = in_sizes[0] / DIM;        // 200000
    const int E = in_sizes[1] / 2;          // 1250000
    const int P = out_size;                 // 4096 * 101
    const int NB = (N + 255) >> BSHIFT;     // 782 coarse buckets
    const int nblocks = (E + CHUNK - 1) / CHUNK;  // 306 edge chunks
    const int M = NB * nblocks;             // 239292 scan entries
    const int nt = (M + 1023) / 1024;       // 234 scan tiles (<=256)

    const int* row = edge_index;            // sources
    const int* col = edge_index + E;        // targets

    const size_t zbytes = (size_t)N * DIM * 2;  // bf16 row buffer (25.6 MB)

    auto align256 = [](size_t x) { return (x + 255) & ~(size_t)255; };
    char* ws = (char*)d_ws;
    uint4* z0   = (uint4*)ws; ws += align256(zbytes);
    uint4* z1   = (uint4*)ws; ws += align256(zbytes);
    uint4* z2   = (uint4*)ws; ws += align256(zbytes);
    uint4* accb = (uint4*)ws; ws += align256(zbytes);
    unsigned* pairs = (unsigned*)ws; ws += align256((size_t)E * 4);
    int* csr_src    = (int*)ws;      ws += align256((size_t)E * 4);
    int* row_ptr    = (int*)ws;      ws += align256((size_t)(N + 1) * 4);
    int* H          = (int*)ws;      ws += align256((size_t)M * 4);
    int* S          = (int*)ws;      ws += align256((size_t)M * 4);
    int* T          = (int*)ws;      ws += align256(256 * 4);
    int* bbase      = (int*)ws;

    // --- deterministic radix CSR build (no memsets, no global atomics) ---
    block_hist_kernel<<<nblocks, 256, 0, stream>>>(col, H, E, NB, nblocks);
    scan_tile_sum_kernel<<<nt, 256, 0, stream>>>(H, T, M);
    scan_tile_offsets_kernel<<<1, 256, 0, stream>>>(T, nt);
    scan_final_kernel<<<nt, 256, 0, stream>>>(H, T, S, bbase, M, nblocks, NB, E);
    scatter_binned_kernel<<<nblocks, 256, 0, stream>>>(row, col, S, pairs, E,
                                                       NB, nblocks);
    // fine_fill also writes z0 = deg^{-1/2} * emb (folded prescale)
    fine_fill_kernel<<<NB, 256, 0, stream>>>(pairs, bbase, row_ptr, csr_src,
                                             (const float4*)emb, z0, N, E);

    const int nodeBlocks = (N * 8 + 255) / 256;  // 8-lane group per node

    // --- layers 1,2 pull-SpMM; layer 3 fused with combine ---
    spmm_pull_kernel<<<nodeBlocks, 256, 0, stream>>>(row_ptr, csr_src, z0, z1, N);
    spmm_pull_kernel<<<nodeBlocks, 256, 0, stream>>>(row_ptr, csr_src, z1, z2, N);
    spmm_combine_kernel<<<nodeBlocks, 256, 0, stream>>>(row_ptr, csr_src, z2,
                                                        z1, (const float4*)emb,
                                                        accb, N);

    // --- scoring ---
    score_kernel<<<(P * 8 + 255) / 256, 256, 0, stream>>>(batch, accb, out, P);
}

// Round 7
// 249.569 us; speedup vs baseline: 1.1361x; 1.0145x over previous
//
#include <hip/hip_runtime.h>

#define DIM 64
#define BSHIFT 8                 // bucket = dst >> 8  (node range 256/bucket)
#define MAXNB 1024               // max coarse buckets (N <= 262144)
#define CHUNK 4096               // edges per block in hist/scatter passes
#define EPT (CHUNK / 256)        // edges per thread in those passes (=16)

// ---------------------------------------------------------------------------
// bf16 helpers (OCP bf16 = top 16 bits of fp32, RNE)
// ---------------------------------------------------------------------------
__device__ inline unsigned packbf(float a, float b) {
    unsigned ua = __float_as_uint(a), ub = __float_as_uint(b);
    unsigned ra = (ua + 0x7FFFu + ((ua >> 16) & 1u)) >> 16;
    unsigned rb = (ub + 0x7FFFu + ((ub >> 16) & 1u)) >> 16;
    return ra | (rb << 16);
}
__device__ inline void unpackbf(unsigned u, float& lo, float& hi) {
    lo = __uint_as_float(u << 16);
    hi = __uint_as_float(u & 0xFFFF0000u);
}
// s[0..7] += 8 bf16 (one uint4)
__device__ inline void acc_row(const uint4 v, float* s) {
    float lo, hi;
    unpackbf(v.x, lo, hi); s[0] += lo; s[1] += hi;
    unpackbf(v.y, lo, hi); s[2] += lo; s[3] += hi;
    unpackbf(v.z, lo, hi); s[4] += lo; s[5] += hi;
    unpackbf(v.w, lo, hi); s[6] += lo; s[7] += hi;
}
// s[0..7] += m * (8 bf16)   (m = 0/1 tail mask -> fma, no branch)
__device__ inline void acc_row_m(const uint4 v, float m, float* s) {
    float lo, hi;
    unpackbf(v.x, lo, hi); s[0] = fmaf(m, lo, s[0]); s[1] = fmaf(m, hi, s[1]);
    unpackbf(v.y, lo, hi); s[2] = fmaf(m, lo, s[2]); s[3] = fmaf(m, hi, s[3]);
    unpackbf(v.z, lo, hi); s[4] = fmaf(m, lo, s[4]); s[5] = fmaf(m, hi, s[5]);
    unpackbf(v.w, lo, hi); s[6] = fmaf(m, lo, s[6]); s[7] = fmaf(m, hi, s[7]);
}

// ---------------------------------------------------------------------------
// K1: per-block bucket histogram.  H[k*nblocks + b] = count of chunk-b edges
// with dst-bucket k.  (bucket-major so the global scan yields contiguous
// bucket ranges)
// ---------------------------------------------------------------------------
__global__ __launch_bounds__(256) void block_hist_kernel(
        const int* __restrict__ col, int* __restrict__ H, int E, int NB,
        int nblocks) {
    __shared__ int h[MAXNB];
    int tid = threadIdx.x;
    for (int k = tid; k < NB; k += 256) h[k] = 0;
    __syncthreads();
    int base = blockIdx.x * CHUNK;
    #pragma unroll
    for (int k = 0; k < EPT; k++) {
        int e = base + tid + k * 256;
        if (e < E) atomicAdd(&h[col[e] >> BSHIFT], 1);
    }
    __syncthreads();
    for (int k = tid; k < NB; k += 256) H[(size_t)k * nblocks + blockIdx.x] = h[k];
}

// ---------------------------------------------------------------------------
// K2/K3/K4: 3-kernel exclusive scan of H[0..M) -> S ; T = tile sums (<=256)
// tiles are 1024 elements (4/thread) so nt <= 256 at CHUNK=4096
// ---------------------------------------------------------------------------
__global__ void scan_tile_sum_kernel(const int* __restrict__ H,
                                     int* __restrict__ T, int M) {
    int tid = threadIdx.x;
    int base = blockIdx.x * 1024 + tid * 4;
    int s = 0;
    #pragma unroll
    for (int k = 0; k < 4; k++)
        if (base + k < M) s += H[base + k];
    __shared__ int lds[256];
    lds[tid] = s;
    __syncthreads();
    for (int off = 128; off > 0; off >>= 1) {
        if (tid < off) lds[tid] += lds[tid + off];
        __syncthreads();
    }
    if (tid == 0) T[blockIdx.x] = lds[0];
}

__global__ void scan_tile_offsets_kernel(int* __restrict__ T, int nt) {
    __shared__ int lds[256];
    int tid = threadIdx.x;
    int v = (tid < nt) ? T[tid] : 0;
    lds[tid] = v;
    __syncthreads();
    for (int off = 1; off < 256; off <<= 1) {
        int t = (tid >= off) ? lds[tid - off] : 0;
        __syncthreads();
        lds[tid] += t;
        __syncthreads();
    }
    if (tid < nt) T[tid] = lds[tid] - v;  // exclusive
}

// also emits bbase[k] = S[k*nblocks] and bbase[NB] = E (folds old bbase launch)
__global__ void scan_final_kernel(const int* __restrict__ H,
                                  const int* __restrict__ T,
                                  int* __restrict__ S,
                                  int* __restrict__ bbase, int M, int nblocks,
                                  int NB, int E) {
    int tid = threadIdx.x;
    int base = blockIdx.x * 1024 + tid * 4;
    int c[4];
    int local = 0;
    #pragma unroll
    for (int k = 0; k < 4; k++) {
        c[k] = (base + k < M) ? H[base + k] : 0;
        local += c[k];
    }
    __shared__ int lds[256];
    lds[tid] = local;
    __syncthreads();
    for (int off = 1; off < 256; off <<= 1) {
        int t = (tid >= off) ? lds[tid - off] : 0;
        __syncthreads();
        lds[tid] += t;
        __syncthreads();
    }
    int excl = lds[tid] - local + T[blockIdx.x];
    #pragma unroll
    for (int k = 0; k < 4; k++) {
        int idx = base + k;
        if (idx < M) {
            S[idx] = excl;
            if (idx % nblocks == 0) bbase[idx / nblocks] = excl;
        }
        excl += c[k];
    }
    if (blockIdx.x == 0 && tid == 0) bbase[NB] = E;
}

// ---------------------------------------------------------------------------
// K5: deterministic binned scatter. Bases come from S — zero global atomics.
// pairs[pos] = src | (dst_local << 24)
// ---------------------------------------------------------------------------
__global__ __launch_bounds__(256) void scatter_binned_kernel(
        const int* __restrict__ row, const int* __restrict__ col,
        const int* __restrict__ S, unsigned* __restrict__ pairs, int E,
        int NB, int nblocks) {
    __shared__ unsigned stage[CHUNK];
    __shared__ int gdst[CHUNK];
    __shared__ int hist[MAXNB];   // counts -> local cursor
    __shared__ int pfx[MAXNB];    // exclusive local prefix
    __shared__ int gbase[MAXNB];  // per-(block,bucket) base (scan scratch too)
    int tid = threadIdx.x;
    int bid = blockIdx.x;
    int base = bid * CHUNK;
    int nloc = min(CHUNK, E - base);

    for (int b = tid; b < NB; b += 256) hist[b] = 0;
    __syncthreads();

    unsigned vals[EPT];
    int keys[EPT];
    #pragma unroll
    for (int k = 0; k < EPT; k++) {
        int e = base + tid + k * 256;
        if (e < E) {
            int d = col[e];
            int s = row[e];
            keys[k] = d >> BSHIFT;
            vals[k] = (unsigned)s | ((unsigned)(d & 255) << 24);
            atomicAdd(&hist[keys[k]], 1);
        } else {
            keys[k] = -1;
        }
    }
    __syncthreads();

    // exclusive scan of hist -> pfx (4 buckets/thread; scratch = gbase)
    int b0 = tid * 4;
    int c4[4];
    int loc = 0;
    #pragma unroll
    for (int k = 0; k < 4; k++) {
        c4[k] = (b0 + k < NB) ? hist[b0 + k] : 0;
        loc += c4[k];
    }
    gbase[tid] = loc;
    __syncthreads();
    for (int off = 1; off < 256; off <<= 1) {
        int t = (tid >= off) ? gbase[tid - off] : 0;
        __syncthreads();
        gbase[tid] += t;
        __syncthreads();
    }
    int excl = gbase[tid] - loc;
    #pragma unroll
    for (int k = 0; k < 4; k++) {
        if (b0 + k < NB) pfx[b0 + k] = excl;
        excl += c4[k];
    }
    __syncthreads();

    // deterministic global bases + init local cursors
    for (int b = tid; b < NB; b += 256) {
        gbase[b] = S[(size_t)b * nblocks + bid];
        hist[b] = pfx[b];
    }
    __syncthreads();

    // bin into LDS (bucket-sorted)
    #pragma unroll
    for (int k = 0; k < EPT; k++) {
        if (keys[k] >= 0) {
            int slot = atomicAdd(&hist[keys[k]], 1);
            stage[slot] = vals[k];
            gdst[slot] = gbase[keys[k]] + (slot - pfx[keys[k]]);
        }
    }
    __syncthreads();

    // sequential runs per bucket
    for (int s = tid; s < nloc; s += 256) pairs[gdst[s]] = stage[s];
}

// ---------------------------------------------------------------------------
// K6: fine fill — one workgroup per bucket; LDS count/scan/cursors;
// produces row_ptr (degree = diff) and dst-grouped csr_src, AND writes
// z0 = deg^{-1/2} * emb (bf16) for its 256 nodes (folded prescale —
// the streaming emb reads overlap the LDS-atomic/scatter latency).
// ---------------------------------------------------------------------------
__global__ __launch_bounds__(256) void fine_fill_kernel(
        const unsigned* __restrict__ pairs, const int* __restrict__ bbase,
        int* __restrict__ row_ptr, int* __restrict__ csr_src,
        const float4* __restrict__ emb4, uint4* __restrict__ z4, int N,
        int E) {
    __shared__ int cnt[256];
    __shared__ int cur[256];
    __shared__ float wds[256];
    int b = blockIdx.x;
    int tid = threadIdx.x;
    int beg = bbase[b], end = bbase[b + 1];
    cnt[tid] = 0;
    __syncthreads();
    for (int j = beg + tid; j < end; j += 256)
        atomicAdd(&cnt[pairs[j] >> 24], 1);
    __syncthreads();
    int v = cnt[tid];
    wds[tid] = (v > 0) ? rsqrtf((float)v) : 0.0f;
    for (int off = 1; off < 256; off <<= 1) {
        int t = (tid >= off) ? cnt[tid - off] : 0;
        __syncthreads();
        cnt[tid] += t;
        __syncthreads();
    }
    int excl = cnt[tid] - v;
    int node0 = (b << BSHIFT) + tid;
    if (node0 < N) row_ptr[node0] = beg + excl;
    cur[tid] = beg + excl;
    __syncthreads();
    for (int j = beg + tid; j < end; j += 256) {
        unsigned p = pairs[j];
        int pos = atomicAdd(&cur[p >> 24], 1);
        csr_src[pos] = (int)(p & 0xFFFFFFu);
    }
    if (b == 0 && tid == 0) row_ptr[N] = E;

    // folded prescale: 8-lane group per node, 32 nodes per pass
    int gl = tid & 7;
    #pragma unroll
    for (int g = 0; g < 8; g++) {
        int il = g * 32 + (tid >> 3);
        int node = (b << BSHIFT) + il;
        if (node < N) {
            float wd = wds[il];
            size_t eo = (size_t)node * 16 + gl * 2;
            float4 a = emb4[eo], c = emb4[eo + 1];
            uint4 z;
            z.x = packbf(a.x * wd, a.y * wd);
            z.y = packbf(a.z * wd, a.w * wd);
            z.z = packbf(c.x * wd, c.y * wd);
            z.w = packbf(c.z * wd, c.w * wd);
            z4[(size_t)node * 8 + gl] = z;
        }
    }
}

// ---------------------------------------------------------------------------
// software-pipelined gather-sum over one CSR row (8-lane group) on bf16 rows:
// clamped-index quads (tail masked by fma), next quad's indices prefetched
// while current gathers are in flight.
// ---------------------------------------------------------------------------
__device__ inline void row_gather_sum(const int* __restrict__ csr_src,
                                      const uint4* __restrict__ z4, int b,
                                      int e, int gl, float* s) {
    if (b >= e) return;
    int e1 = e - 1;
    int j = b;
    int i0 = csr_src[j];
    int i1 = csr_src[min(j + 1, e1)];
    int i2 = csr_src[min(j + 2, e1)];
    int i3 = csr_src[min(j + 3, e1)];
    while (j < e) {
        uint4 v0 = z4[(size_t)i0 * 8 + gl];
        uint4 v1 = z4[(size_t)i1 * 8 + gl];
        uint4 v2 = z4[(size_t)i2 * 8 + gl];
        uint4 v3 = z4[(size_t)i3 * 8 + gl];
        int jn = j + 4;
        if (jn < e) {  // prefetch next quad (independent of gathers above)
            i0 = csr_src[jn];
            i1 = csr_src[min(jn + 1, e1)];
            i2 = csr_src[min(jn + 2, e1)];
            i3 = csr_src[min(jn + 3, e1)];
        }
        float m1 = (j + 1 < e) ? 1.0f : 0.0f;
        float m2 = (j + 2 < e) ? 1.0f : 0.0f;
        float m3 = (j + 3 < e) ? 1.0f : 0.0f;
        acc_row(v0, s);
        acc_row_m(v1, m1, s);
        acc_row_m(v2, m2, s);
        acc_row_m(v3, m3, s);
        j = jn;
    }
}

// ---------------------------------------------------------------------------
// pull SpMM on bf16 z:  z_next[i] = (sum z[src]) / deg
// ---------------------------------------------------------------------------
__global__ __launch_bounds__(256) void spmm_pull_kernel(
        const int* __restrict__ row_ptr, const int* __restrict__ csr_src,
        const uint4* __restrict__ z4, uint4* __restrict__ znext4, int N) {
    int t = blockIdx.x * blockDim.x + threadIdx.x;
    int i = t >> 3;
    int gl = t & 7;
    if (i >= N) return;
    int b = row_ptr[i], e = row_ptr[i + 1];
    float s[8] = {0, 0, 0, 0, 0, 0, 0, 0};
    row_gather_sum(csr_src, z4, b, e, gl, s);
    int deg = e - b;
    float wd = (deg > 0) ? rsqrtf((float)deg) : 0.0f;
    float w2 = wd * wd;
    uint4 z;
    z.x = packbf(s[0] * w2, s[1] * w2);
    z.y = packbf(s[2] * w2, s[3] * w2);
    z.z = packbf(s[4] * w2, s[5] * w2);
    z.w = packbf(s[6] * w2, s[7] * w2);
    znext4[(size_t)i * 8 + gl] = z;
}

// ---------------------------------------------------------------------------
// fused layer-3 SpMM + combine:
//   t = sum_{nbr} z2[src];  acc = emb + sqrt(deg)*(z1+z2) + wd*t   (bf16)
// ---------------------------------------------------------------------------
__global__ __launch_bounds__(256) void spmm_combine_kernel(
        const int* __restrict__ row_ptr, const int* __restrict__ csr_src,
        const uint4* __restrict__ z2, const uint4* __restrict__ z1,
        const float4* __restrict__ emb4, uint4* __restrict__ accb, int N) {
    int t = blockIdx.x * blockDim.x + threadIdx.x;
    int i = t >> 3;
    int gl = t & 7;
    if (i >= N) return;
    int b = row_ptr[i], e = row_ptr[i + 1];
    float s[8] = {0, 0, 0, 0, 0, 0, 0, 0};
    row_gather_sum(csr_src, z2, b, e, gl, s);
    int deg = e - b;
    float wd = (deg > 0) ? rsqrtf((float)deg) : 0.0f;
    float sq = (deg > 0) ? sqrtf((float)deg) : 0.0f;
    size_t zo = (size_t)i * 8 + gl;
    uint4 a1 = z1[zo], a2 = z2[zo];
    float w[8] = {0, 0, 0, 0, 0, 0, 0, 0};
    acc_row(a1, w); acc_row(a2, w);
    size_t eo = (size_t)i * 16 + gl * 2;
    float4 e0 = emb4[eo], e1 = emb4[eo + 1];
    float r0 = e0.x + sq * w[0] + wd * s[0];
    float r1 = e0.y + sq * w[1] + wd * s[1];
    float r2 = e0.z + sq * w[2] + wd * s[2];
    float r3 = e0.w + sq * w[3] + wd * s[3];
    float r4 = e1.x + sq * w[4] + wd * s[4];
    float r5 = e1.y + sq * w[5] + wd * s[5];
    float r6 = e1.z + sq * w[6] + wd * s[6];
    float r7 = e1.w + sq * w[7] + wd * s[7];
    uint4 z;
    z.x = packbf(r0, r1);
    z.y = packbf(r2, r3);
    z.z = packbf(r4, r5);
    z.w = packbf(r6, r7);
    accb[zo] = z;
}

// ---------------------------------------------------------------------------
// logits[p] = alpha^2 * dot(acc[u], acc[i]) ; 8-lane group per pair
// ---------------------------------------------------------------------------
__global__ __launch_bounds__(256) void score_kernel(
        const int* __restrict__ batch, const uint4* __restrict__ accb,
        float* __restrict__ out, int P) {
    int t = blockIdx.x * blockDim.x + threadIdx.x;
    int p = t >> 3;
    int gl = t & 7;
    if (p >= P) return;
    int u = batch[(size_t)p * 3 + 0];
    int it = batch[(size_t)p * 3 + 1];
    uint4 a = accb[(size_t)u * 8 + gl];
    uint4 b = accb[(size_t)it * 8 + gl];
    float sa[8] = {0, 0, 0, 0, 0, 0, 0, 0};
    float sb[8] = {0, 0, 0, 0, 0, 0, 0, 0};
    acc_row(a, sa);
    acc_row(b, sb);
    float s = sa[0] * sb[0] + sa[1] * sb[1] + sa[2] * sb[2] + sa[3] * sb[3] +
              sa[4] * sb[4] + sa[5] * sb[5] + sa[6] * sb[6] + sa[7] * sb[7];
    s += __shfl_xor(s, 4, 64);
    s += __shfl_xor(s, 2, 64);
    s += __shfl_xor(s, 1, 64);
    if (gl == 0) out[p] = s * 0.0625f;  // alpha^2, alpha = 1/(K_LAYERS+1)
}

extern "C" void kernel_launch(void* const* d_in, const int* in_sizes, int n_in,
                              void* d_out, int out_size, void* d_ws,
                              size_t ws_size, hipStream_t stream) {
    const float* emb = (const float*)d_in[0];
    const int* edge_index = (const int*)d_in[1];
    const int* batch = (const int*)d_in[2];
    float* out = (float*)d_out;

    const int N = in_sizes[0] / DIM;        // 200000
    const int E = in_sizes[1] / 2;          // 1250000
    const int P = out_size;                 // 4096 * 101
    const int NB = (N + 255) >> BSHIFT;     // 782 coarse buckets
    const int nblocks = (E + CHUNK - 1) / CHUNK;  // 306 edge chunks
    const int M = NB * nblocks;             // 239292 scan entries
    const int nt = (M + 1023) / 1024;       // 234 scan tiles (<=256)

    const int* row = edge_index;            // sources
    const int* col = edge_index + E;        // targets

    const size_t zbytes = (size_t)N * DIM * 2;  // bf16 row buffer (25.6 MB)

    auto align256 = [](size_t x) { return (x + 255) & ~(size_t)255; };
    char* ws = (char*)d_ws;
    uint4* z0   = (uint4*)ws; ws += align256(zbytes);
    uint4* z1   = (uint4*)ws; ws += align256(zbytes);
    uint4* z2   = (uint4*)ws; ws += align256(zbytes);
    uint4* accb = (uint4*)ws; ws += align256(zbytes);
    unsigned* pairs = (unsigned*)ws; ws += align256((size_t)E * 4);
    int* csr_src    = (int*)ws;      ws += align256((size_t)E * 4);
    int* row_ptr    = (int*)ws;      ws += align256((size_t)(N + 1) * 4);
    int* H          = (int*)ws;      ws += align256((size_t)M * 4);
    int* S          = (int*)ws;      ws += align256((size_t)M * 4);
    int* T          = (int*)ws;      ws += align256(256 * 4);
    int* bbase      = (int*)ws;

    // --- deterministic radix CSR build (no memsets, no global atomics) ---
    block_hist_kernel<<<nblocks, 256, 0, stream>>>(col, H, E, NB, nblocks);
    scan_tile_sum_kernel<<<nt, 256, 0, stream>>>(H, T, M);
    scan_tile_offsets_kernel<<<1, 256, 0, stream>>>(T, nt);
    scan_final_kernel<<<nt, 256, 0, stream>>>(H, T, S, bbase, M, nblocks, NB, E);
    scatter_binned_kernel<<<nblocks, 256, 0, stream>>>(row, col, S, pairs, E,
                                                       NB, nblocks);
    // fine_fill also writes z0 = deg^{-1/2} * emb (folded prescale)
    fine_fill_kernel<<<NB, 256, 0, stream>>>(pairs, bbase, row_ptr, csr_src,
                                             (const float4*)emb, z0, N, E);

    const int nodeBlocks = (N * 8 + 255) / 256;  // 8-lane group per node

    // --- layers 1,2 pull-SpMM; layer 3 fused with combine ---
    spmm_pull_kernel<<<nodeBlocks, 256, 0, stream>>>(row_ptr, csr_src, z0, z1, N);
    spmm_pull_kernel<<<nodeBlocks, 256, 0, stream>>>(row_ptr, csr_src, z1, z2, N);
    spmm_combine_kernel<<<nodeBlocks, 256, 0, stream>>>(row_ptr, csr_src, z2,
                                                        z1, (const float4*)emb,
                                                        accb, N);

    // --- scoring ---
    score_kernel<<<(P * 8 + 255) / 256, 256, 0, stream>>>(batch, accb, out, P);
}

// Round 9
// 249.411 us; speedup vs baseline: 1.1368x; 1.0006x over previous
//
#include <hip/hip_runtime.h>

#define DIM 64
#define BSHIFT 8                 // bucket = dst >> 8  (node range 256/bucket)
#define MAXNB 1024               // max coarse buckets (N <= 262144)
#define CHUNK 4096               // edges per block in hist/scatter passes
#define EPT (CHUNK / 256)        // edges per thread in those passes (=16)

// ---------------------------------------------------------------------------
// bf16 helpers (OCP bf16 = top 16 bits of fp32, RNE)
// ---------------------------------------------------------------------------
__device__ inline unsigned packbf(float a, float b) {
    unsigned ua = __float_as_uint(a), ub = __float_as_uint(b);
    unsigned ra = (ua + 0x7FFFu + ((ua >> 16) & 1u)) >> 16;
    unsigned rb = (ub + 0x7FFFu + ((ub >> 16) & 1u)) >> 16;
    return ra | (rb << 16);
}
__device__ inline void unpackbf(unsigned u, float& lo, float& hi) {
    lo = __uint_as_float(u << 16);
    hi = __uint_as_float(u & 0xFFFF0000u);
}
// s[0..7] += 8 bf16 (one uint4)
__device__ inline void acc_row(const uint4 v, float* s) {
    float lo, hi;
    unpackbf(v.x, lo, hi); s[0] += lo; s[1] += hi;
    unpackbf(v.y, lo, hi); s[2] += lo; s[3] += hi;
    unpackbf(v.z, lo, hi); s[4] += lo; s[5] += hi;
    unpackbf(v.w, lo, hi); s[6] += lo; s[7] += hi;
}
// s[0..7] += m * (8 bf16)   (m = 0/1 tail mask -> fma, no branch)
__device__ inline void acc_row_m(const uint4 v, float m, float* s) {
    float lo, hi;
    unpackbf(v.x, lo, hi); s[0] = fmaf(m, lo, s[0]); s[1] = fmaf(m, hi, s[1]);
    unpackbf(v.y, lo, hi); s[2] = fmaf(m, lo, s[2]); s[3] = fmaf(m, hi, s[3]);
    unpackbf(v.z, lo, hi); s[4] = fmaf(m, lo, s[4]); s[5] = fmaf(m, hi, s[5]);
    unpackbf(v.w, lo, hi); s[6] = fmaf(m, lo, s[6]); s[7] = fmaf(m, hi, s[7]);
}

// ---------------------------------------------------------------------------
// K1: per-block bucket histogram.  H[k*nblocks + b] = count of chunk-b edges
// with dst-bucket k.  (bucket-major so the global scan yields contiguous
// bucket ranges)
// ---------------------------------------------------------------------------
__global__ __launch_bounds__(256) void block_hist_kernel(
        const int* __restrict__ col, int* __restrict__ H, int E, int NB,
        int nblocks) {
    __shared__ int h[MAXNB];
    int tid = threadIdx.x;
    for (int k = tid; k < NB; k += 256) h[k] = 0;
    __syncthreads();
    int base = blockIdx.x * CHUNK;
    #pragma unroll
    for (int k = 0; k < EPT; k++) {
        int e = base + tid + k * 256;
        if (e < E) atomicAdd(&h[col[e] >> BSHIFT], 1);
    }
    __syncthreads();
    for (int k = tid; k < NB; k += 256) H[(size_t)k * nblocks + blockIdx.x] = h[k];
}

// ---------------------------------------------------------------------------
// K2/K3/K4: 3-kernel exclusive scan of H[0..M) -> S ; T = tile sums (<=256)
// tiles are 1024 elements (4/thread) so nt <= 256 at CHUNK=4096
// ---------------------------------------------------------------------------
__global__ void scan_tile_sum_kernel(const int* __restrict__ H,
                                     int* __restrict__ T, int M) {
    int tid = threadIdx.x;
    int base = blockIdx.x * 1024 + tid * 4;
    int s = 0;
    #pragma unroll
    for (int k = 0; k < 4; k++)
        if (base + k < M) s += H[base + k];
    __shared__ int lds[256];
    lds[tid] = s;
    __syncthreads();
    for (int off = 128; off > 0; off >>= 1) {
        if (tid < off) lds[tid] += lds[tid + off];
        __syncthreads();
    }
    if (tid == 0) T[blockIdx.x] = lds[0];
}

__global__ void scan_tile_offsets_kernel(int* __restrict__ T, int nt) {
    __shared__ int lds[256];
    int tid = threadIdx.x;
    int v = (tid < nt) ? T[tid] : 0;
    lds[tid] = v;
    __syncthreads();
    for (int off = 1; off < 256; off <<= 1) {
        int t = (tid >= off) ? lds[tid - off] : 0;
        __syncthreads();
        lds[tid] += t;
        __syncthreads();
    }
    if (tid < nt) T[tid] = lds[tid] - v;  // exclusive
}

// also emits bbase[k] = S[k*nblocks] and bbase[NB] = E (folds old bbase launch)
__global__ void scan_final_kernel(const int* __restrict__ H,
                                  const int* __restrict__ T,
                                  int* __restrict__ S,
                                  int* __restrict__ bbase, int M, int nblocks,
                                  int NB, int E) {
    int tid = threadIdx.x;
    int base = blockIdx.x * 1024 + tid * 4;
    int c[4];
    int local = 0;
    #pragma unroll
    for (int k = 0; k < 4; k++) {
        c[k] = (base + k < M) ? H[base + k] : 0;
        local += c[k];
    }
    __shared__ int lds[256];
    lds[tid] = local;
    __syncthreads();
    for (int off = 1; off < 256; off <<= 1) {
        int t = (tid >= off) ? lds[tid - off] : 0;
        __syncthreads();
        lds[tid] += t;
        __syncthreads();
    }
    int excl = lds[tid] - local + T[blockIdx.x];
    #pragma unroll
    for (int k = 0; k < 4; k++) {
        int idx = base + k;
        if (idx < M) {
            S[idx] = excl;
            if (idx % nblocks == 0) bbase[idx / nblocks] = excl;
        }
        excl += c[k];
    }
    if (blockIdx.x == 0 && tid == 0) bbase[NB] = E;
}

// ---------------------------------------------------------------------------
// K5: deterministic binned scatter. Bases come from S — zero global atomics.
// pairs[pos] = src | (dst_local << 24)
// ---------------------------------------------------------------------------
__global__ __launch_bounds__(256) void scatter_binned_kernel(
        const int* __restrict__ row, const int* __restrict__ col,
        const int* __restrict__ S, unsigned* __restrict__ pairs, int E,
        int NB, int nblocks) {
    __shared__ unsigned stage[CHUNK];
    __shared__ int gdst[CHUNK];
    __shared__ int hist[MAXNB];   // counts -> local cursor
    __shared__ int pfx[MAXNB];    // exclusive local prefix
    __shared__ int gbase[MAXNB];  // per-(block,bucket) base (scan scratch too)
    int tid = threadIdx.x;
    int bid = blockIdx.x;
    int base = bid * CHUNK;
    int nloc = min(CHUNK, E - base);

    for (int b = tid; b < NB; b += 256) hist[b] = 0;
    __syncthreads();

    unsigned vals[EPT];
    int keys[EPT];
    #pragma unroll
    for (int k = 0; k < EPT; k++) {
        int e = base + tid + k * 256;
        if (e < E) {
            int d = col[e];
            int s = row[e];
            keys[k] = d >> BSHIFT;
            vals[k] = (unsigned)s | ((unsigned)(d & 255) << 24);
            atomicAdd(&hist[keys[k]], 1);
        } else {
            keys[k] = -1;
        }
    }
    __syncthreads();

    // exclusive scan of hist -> pfx (4 buckets/thread; scratch = gbase)
    int b0 = tid * 4;
    int c4[4];
    int loc = 0;
    #pragma unroll
    for (int k = 0; k < 4; k++) {
        c4[k] = (b0 + k < NB) ? hist[b0 + k] : 0;
        loc += c4[k];
    }
    gbase[tid] = loc;
    __syncthreads();
    for (int off = 1; off < 256; off <<= 1) {
        int t = (tid >= off) ? gbase[tid - off] : 0;
        __syncthreads();
        gbase[tid] += t;
        __syncthreads();
    }
    int excl = gbase[tid] - loc;
    #pragma unroll
    for (int k = 0; k < 4; k++) {
        if (b0 + k < NB) pfx[b0 + k] = excl;
        excl += c4[k];
    }
    __syncthreads();

    // deterministic global bases + init local cursors
    for (int b = tid; b < NB; b += 256) {
        gbase[b] = S[(size_t)b * nblocks + bid];
        hist[b] = pfx[b];
    }
    __syncthreads();

    // bin into LDS (bucket-sorted)
    #pragma unroll
    for (int k = 0; k < EPT; k++) {
        if (keys[k] >= 0) {
            int slot = atomicAdd(&hist[keys[k]], 1);
            stage[slot] = vals[k];
            gdst[slot] = gbase[keys[k]] + (slot - pfx[keys[k]]);
        }
    }
    __syncthreads();

    // sequential runs per bucket
    for (int s = tid; s < nloc; s += 256) pairs[gdst[s]] = stage[s];
}

// ---------------------------------------------------------------------------
// K6: fine fill — one workgroup per bucket; LDS count/scan/cursors;
// produces row_ptr (degree = diff) and dst-grouped csr_src, AND writes
// z0 = deg^{-1/2} * emb (bf16) for its 256 nodes (folded prescale —
// the streaming emb reads overlap the LDS-atomic/scatter latency).
// ---------------------------------------------------------------------------
__global__ __launch_bounds__(256) void fine_fill_kernel(
        const unsigned* __restrict__ pairs, const int* __restrict__ bbase,
        int* __restrict__ row_ptr, int* __restrict__ csr_src,
        const float4* __restrict__ emb4, uint4* __restrict__ z4, int N,
        int E) {
    __shared__ int cnt[256];
    __shared__ int cur[256];
    __shared__ float wds[256];
    int b = blockIdx.x;
    int tid = threadIdx.x;
    int beg = bbase[b], end = bbase[b + 1];
    cnt[tid] = 0;
    __syncthreads();
    for (int j = beg + tid; j < end; j += 256)
        atomicAdd(&cnt[pairs[j] >> 24], 1);
    __syncthreads();
    int v = cnt[tid];
    wds[tid] = (v > 0) ? rsqrtf((float)v) : 0.0f;
    for (int off = 1; off < 256; off <<= 1) {
        int t = (tid >= off) ? cnt[tid - off] : 0;
        __syncthreads();
        cnt[tid] += t;
        __syncthreads();
    }
    int excl = cnt[tid] - v;
    int node0 = (b << BSHIFT) + tid;
    if (node0 < N) row_ptr[node0] = beg + excl;
    cur[tid] = beg + excl;
    __syncthreads();
    for (int j = beg + tid; j < end; j += 256) {
        unsigned p = pairs[j];
        int pos = atomicAdd(&cur[p >> 24], 1);
        csr_src[pos] = (int)(p & 0xFFFFFFu);
    }
    if (b == 0 && tid == 0) row_ptr[N] = E;

    // folded prescale: 8-lane group per node, 32 nodes per pass
    int gl = tid & 7;
    #pragma unroll
    for (int g = 0; g < 8; g++) {
        int il = g * 32 + (tid >> 3);
        int node = (b << BSHIFT) + il;
        if (node < N) {
            float wd = wds[il];
            size_t eo = (size_t)node * 16 + gl * 2;
            float4 a = emb4[eo], c = emb4[eo + 1];
            uint4 z;
            z.x = packbf(a.x * wd, a.y * wd);
            z.y = packbf(a.z * wd, a.w * wd);
            z.z = packbf(c.x * wd, c.y * wd);
            z.w = packbf(c.z * wd, c.w * wd);
            z4[(size_t)node * 8 + gl] = z;
        }
    }
}

// ---------------------------------------------------------------------------
// software-pipelined gather-sum over one CSR row (8-lane group) on bf16 rows:
// clamped-index quads (tail masked by fma), next quad's indices prefetched
// while current gathers are in flight.
// ---------------------------------------------------------------------------
__device__ inline void row_gather_sum(const int* __restrict__ csr_src,
                                      const uint4* __restrict__ z4, int b,
                                      int e, int gl, float* s) {
    if (b >= e) return;
    int e1 = e - 1;
    int j = b;
    int i0 = csr_src[j];
    int i1 = csr_src[min(j + 1, e1)];
    int i2 = csr_src[min(j + 2, e1)];
    int i3 = csr_src[min(j + 3, e1)];
    while (j < e) {
        uint4 v0 = z4[(size_t)i0 * 8 + gl];
        uint4 v1 = z4[(size_t)i1 * 8 + gl];
        uint4 v2 = z4[(size_t)i2 * 8 + gl];
        uint4 v3 = z4[(size_t)i3 * 8 + gl];
        int jn = j + 4;
        if (jn < e) {  // prefetch next quad (independent of gathers above)
            i0 = csr_src[jn];
            i1 = csr_src[min(jn + 1, e1)];
            i2 = csr_src[min(jn + 2, e1)];
            i3 = csr_src[min(jn + 3, e1)];
        }
        float m1 = (j + 1 < e) ? 1.0f : 0.0f;
        float m2 = (j + 2 < e) ? 1.0f : 0.0f;
        float m3 = (j + 3 < e) ? 1.0f : 0.0f;
        acc_row(v0, s);
        acc_row_m(v1, m1, s);
        acc_row_m(v2, m2, s);
        acc_row_m(v3, m3, s);
        j = jn;
    }
}

// ---------------------------------------------------------------------------
// pull SpMM on bf16 z:  z_next[i] = (sum z[src]) / deg
// ---------------------------------------------------------------------------
__global__ __launch_bounds__(256) void spmm_pull_kernel(
        const int* __restrict__ row_ptr, const int* __restrict__ csr_src,
        const uint4* __restrict__ z4, uint4* __restrict__ znext4, int N) {
    int t = blockIdx.x * blockDim.x + threadIdx.x;
    int i = t >> 3;
    int gl = t & 7;
    if (i >= N) return;
    int b = row_ptr[i], e = row_ptr[i + 1];
    float s[8] = {0, 0, 0, 0, 0, 0, 0, 0};
    row_gather_sum(csr_src, z4, b, e, gl, s);
    int deg = e - b;
    float wd = (deg > 0) ? rsqrtf((float)deg) : 0.0f;
    float w2 = wd * wd;
    uint4 z;
    z.x = packbf(s[0] * w2, s[1] * w2);
    z.y = packbf(s[2] * w2, s[3] * w2);
    z.z = packbf(s[4] * w2, s[5] * w2);
    z.w = packbf(s[6] * w2, s[7] * w2);
    znext4[(size_t)i * 8 + gl] = z;
}

// ---------------------------------------------------------------------------
// fused layer-3 SpMM + combine.  emb is reconstructed from z0:
//   z0 = bf16(emb * deg^{-1/2})  =>  emb ~= sqrt(deg) * z0   (deg > 0)
//   acc = sq*(z0 + z1 + z2) + wd*t       (bf16 out)
// This replaces the 51.2 MB fp32 emb stream with the 25.6 MB bf16 z0
// stream (-25.6 MB compulsory traffic).  deg==0 nodes (~0.2%) read emb
// directly (z0 is 0 there).
// ---------------------------------------------------------------------------
__global__ __launch_bounds__(256) void spmm_combine_kernel(
        const int* __restrict__ row_ptr, const int* __restrict__ csr_src,
        const uint4* __restrict__ z2, const uint4* __restrict__ z1,
        const uint4* __restrict__ z0, const float4* __restrict__ emb4,
        uint4* __restrict__ accb, int N) {
    int t = blockIdx.x * blockDim.x + threadIdx.x;
    int i = t >> 3;
    int gl = t & 7;
    if (i >= N) return;
    int b = row_ptr[i], e = row_ptr[i + 1];
    float s[8] = {0, 0, 0, 0, 0, 0, 0, 0};
    row_gather_sum(csr_src, z2, b, e, gl, s);
    int deg = e - b;
    size_t zo = (size_t)i * 8 + gl;
    uint4 zr;
    if (deg > 0) {
        float wd = rsqrtf((float)deg);
        float sq = sqrtf((float)deg);
        uint4 a0 = z0[zo], a1 = z1[zo], a2 = z2[zo];
        float w[8] = {0, 0, 0, 0, 0, 0, 0, 0};
        acc_row(a0, w); acc_row(a1, w); acc_row(a2, w);
        zr.x = packbf(sq * w[0] + wd * s[0], sq * w[1] + wd * s[1]);
        zr.y = packbf(sq * w[2] + wd * s[2], sq * w[3] + wd * s[3]);
        zr.z = packbf(sq * w[4] + wd * s[4], sq * w[5] + wd * s[5]);
        zr.w = packbf(sq * w[6] + wd * s[6], sq * w[7] + wd * s[7]);
    } else {
        // isolated node: acc = emb exactly (all graph terms are zero)
        size_t eo = (size_t)i * 16 + gl * 2;
        float4 e0 = emb4[eo], e1 = emb4[eo + 1];
        zr.x = packbf(e0.x, e0.y);
        zr.y = packbf(e0.z, e0.w);
        zr.z = packbf(e1.x, e1.y);
        zr.w = packbf(e1.z, e1.w);
    }
    accb[zo] = zr;
}

// ---------------------------------------------------------------------------
// logits[p] = alpha^2 * dot(acc[u], acc[i]) ; 8-lane group per pair
// ---------------------------------------------------------------------------
__global__ __launch_bounds__(256) void score_kernel(
        const int* __restrict__ batch, const uint4* __restrict__ accb,
        float* __restrict__ out, int P) {
    int t = blockIdx.x * blockDim.x + threadIdx.x;
    int p = t >> 3;
    int gl = t & 7;
    if (p >= P) return;
    int u = batch[(size_t)p * 3 + 0];
    int it = batch[(size_t)p * 3 + 1];
    uint4 a = accb[(size_t)u * 8 + gl];
    uint4 b = accb[(size_t)it * 8 + gl];
    float sa[8] = {0, 0, 0, 0, 0, 0, 0, 0};
    float sb[8] = {0, 0, 0, 0, 0, 0, 0, 0};
    acc_row(a, sa);
    acc_row(b, sb);
    float s = sa[0] * sb[0] + sa[1] * sb[1] + sa[2] * sb[2] + sa[3] * sb[3] +
              sa[4] * sb[4] + sa[5] * sb[5] + sa[6] * sb[6] + sa[7] * sb[7];
    s += __shfl_xor(s, 4, 64);
    s += __shfl_xor(s, 2, 64);
    s += __shfl_xor(s, 1, 64);
    if (gl == 0) out[p] = s * 0.0625f;  // alpha^2, alpha = 1/(K_LAYERS+1)
}

extern "C" void kernel_launch(void* const* d_in, const int* in_sizes, int n_in,
                              void* d_out, int out_size, void* d_ws,
                              size_t ws_size, hipStream_t stream) {
    const float* emb = (const float*)d_in[0];
    const int* edge_index = (const int*)d_in[1];
    const int* batch = (const int*)d_in[2];
    float* out = (float*)d_out;

    const int N = in_sizes[0] / DIM;        // 200000
    const int E = in_sizes[1] / 2;          // 1250000
    const int P = out_size;                 // 4096 * 101
    const int NB = (N + 255) >> BSHIFT;     // 782 coarse buckets
    const int nblocks = (E + CHUNK - 1) / CHUNK;  // 306 edge chunks
    const int M = NB * nblocks;             // 239292 scan entries
    const int nt = (M + 1023) / 1024;       // 234 scan tiles (<=256)

    const int* row = edge_index;            // sources
    const int* col = edge_index + E;        // targets

    const size_t zbytes = (size_t)N * DIM * 2;  // bf16 row buffer (25.6 MB)

    auto align256 = [](size_t x) { return (x + 255) & ~(size_t)255; };
    char* ws = (char*)d_ws;
    uint4* z0   = (uint4*)ws; ws += align256(zbytes);
    uint4* z1   = (uint4*)ws; ws += align256(zbytes);
    uint4* z2   = (uint4*)ws; ws += align256(zbytes);
    uint4* accb = (uint4*)ws; ws += align256(zbytes);
    unsigned* pairs = (unsigned*)ws; ws += align256((size_t)E * 4);
    int* csr_src    = (int*)ws;      ws += align256((size_t)E * 4);
    int* row_ptr    = (int*)ws;      ws += align256((size_t)(N + 1) * 4);
    int* H          = (int*)ws;      ws += align256((size_t)M * 4);
    int* S          = (int*)ws;      ws += align256((size_t)M * 4);
    int* T          = (int*)ws;      ws += align256(256 * 4);
    int* bbase      = (int*)ws;

    // --- deterministic radix CSR build (no memsets, no global atomics) ---
    block_hist_kernel<<<nblocks, 256, 0, stream>>>(col, H, E, NB, nblocks);
    scan_tile_sum_kernel<<<nt, 256, 0, stream>>>(H, T, M);
    scan_tile_offsets_kernel<<<1, 256, 0, stream>>>(T, nt);
    scan_final_kernel<<<nt, 256, 0, stream>>>(H, T, S, bbase, M, nblocks, NB, E);
    scatter_binned_kernel<<<nblocks, 256, 0, stream>>>(row, col, S, pairs, E,
                                                       NB, nblocks);
    // fine_fill also writes z0 = deg^{-1/2} * emb (folded prescale)
    fine_fill_kernel<<<NB, 256, 0, stream>>>(pairs, bbase, row_ptr, csr_src,
                                             (const float4*)emb, z0, N, E);

    const int nodeBlocks = (N * 8 + 255) / 256;  // 8-lane group per node

    // --- layers 1,2 pull-SpMM; layer 3 fused with combine ---
    spmm_pull_kernel<<<nodeBlocks, 256, 0, stream>>>(row_ptr, csr_src, z0, z1, N);
    spmm_pull_kernel<<<nodeBlocks, 256, 0, stream>>>(row_ptr, csr_src, z1, z2, N);
    spmm_combine_kernel<<<nodeBlocks, 256, 0, stream>>>(row_ptr, csr_src, z2,
                                                        z1, z0,
                                                        (const float4*)emb,
                                                        accb, N);

    // --- scoring ---
    score_kernel<<<(P * 8 + 255) / 256, 256, 0, stream>>>(batch, accb, out, P);
}